// Round 1
// baseline (596.301 us; speedup 1.0000x reference)
//
#include <hip/hip_runtime.h>

#define LC 64
#define NC 32

typedef float f4v __attribute__((ext_vector_type(4)));
typedef short s8v __attribute__((ext_vector_type(8)));

__device__ inline unsigned short f2bf(float x){
  union { float f; unsigned u; } v; v.f = x;
  unsigned r = v.u + 0x7fffu + ((v.u >> 16) & 1u);
  return (unsigned short)(r >> 16);
}
__device__ inline float bf2f(unsigned short b){
  union { unsigned u; float f; } v; v.u = ((unsigned)b) << 16;
  return v.f;
}
__device__ inline unsigned addbf2(unsigned a, unsigned b){
  float lo = bf2f((unsigned short)(a & 0xffffu)) + bf2f((unsigned short)(b & 0xffffu));
  float hi = bf2f((unsigned short)(a >> 16))     + bf2f((unsigned short)(b >> 16));
  return (unsigned)f2bf(lo) | ((unsigned)f2bf(hi) << 16);
}

// ---------------------------------------------------------------------------
// prep: Mt = 0.1*A^T ; T0 = I + Mt/6 ; Bt_bf16[n][k] = B[k][n] ; Ct_bf16[j][n] = C[n][j]
__global__ void k_prep(const float* __restrict__ A, const float* __restrict__ B,
                       const float* __restrict__ C,
                       float* __restrict__ Mt, float* __restrict__ T0,
                       unsigned short* __restrict__ Bt, unsigned short* __restrict__ Ct){
  int i = blockIdx.x * 256 + threadIdx.x;
  const int tot = 65536 + 262144 + 262144;
  for (; i < tot; i += gridDim.x * 256) {
    if (i < 65536) {
      int r = i >> 8, c = i & 255;
      float m = 0.1f * A[c * 256 + r];
      Mt[i] = m;
      T0[i] = m * (1.0f / 6.0f) + (r == c ? 1.0f : 0.0f);
    } else if (i < 65536 + 262144) {
      int j = i - 65536;            // n*1024 + k
      int n = j >> 10, k = j & 1023;
      Bt[j] = f2bf(B[k * 256 + n]);
    } else {
      int j = i - 65536 - 262144;   // col*256 + n
      int col = j >> 8, n = j & 255;
      Ct[j] = f2bf(C[n * 1024 + col]);
    }
  }
}

// ---------------------------------------------------------------------------
// 256x256x256 f32 GEMM via hi/lo bf16 split MFMA:  Cout = alpha*(A@B) + addI*I
__global__ __launch_bounds__(256) void k_gemm256_hl(const float* __restrict__ A,
                                                    const float* __restrict__ B,
                                                    float* __restrict__ Cout,
                                                    float alpha, int addI){
  __shared__ unsigned short Ah[64][40], Al[64][40], Bh[64][40], Bl[64][40];
  int tid = threadIdx.x;
  int m0 = blockIdx.x * 64, n0 = blockIdx.y * 64;
  int w = tid >> 6, lane = tid & 63;
  int wr = w >> 1, wc = w & 1;
  int l15 = lane & 15, quad = lane >> 4;
  int q8 = quad * 8;
  f4v acc[2][2] = {};
  for (int kt = 0; kt < 256; kt += 32) {
    __syncthreads();
    // stage A (f32 -> hi/lo bf16), 64x32
#pragma unroll
    for (int q = 0; q < 2; ++q) {
      int id = q * 256 + tid;        // 0..511
      int row = id >> 3, c4 = id & 7;
      float4 vv = *reinterpret_cast<const float4*>(&A[(m0 + row) * 256 + kt + c4 * 4]);
      float vs[4] = {vv.x, vv.y, vv.z, vv.w};
      ushort4 h4, l4;
      unsigned short* hp = &h4.x; unsigned short* lp = &l4.x;
#pragma unroll
      for (int j = 0; j < 4; ++j) {
        unsigned short hi = f2bf(vs[j]);
        hp[j] = hi;
        lp[j] = f2bf(vs[j] - bf2f(hi));
      }
      *reinterpret_cast<ushort4*>(&Ah[row][c4 * 4]) = h4;
      *reinterpret_cast<ushort4*>(&Al[row][c4 * 4]) = l4;
    }
    // stage B transposed: Btile[col][k], coalesced reads along n
    {
      int col = tid & 63, kk0 = (tid >> 6) * 8;
#pragma unroll
      for (int j = 0; j < 8; ++j) {
        float v = B[(kt + kk0 + j) * 256 + n0 + col];
        unsigned short hi = f2bf(v);
        Bh[col][kk0 + j] = hi;
        Bl[col][kk0 + j] = f2bf(v - bf2f(hi));
      }
    }
    __syncthreads();
#pragma unroll
    for (int aq = 0; aq < 2; ++aq) {
      s8v ah = *reinterpret_cast<const s8v*>(&Ah[wr * 32 + aq * 16 + l15][q8]);
      s8v al = *reinterpret_cast<const s8v*>(&Al[wr * 32 + aq * 16 + l15][q8]);
#pragma unroll
      for (int bq = 0; bq < 2; ++bq) {
        s8v bh = *reinterpret_cast<const s8v*>(&Bh[wc * 32 + bq * 16 + l15][q8]);
        s8v bl = *reinterpret_cast<const s8v*>(&Bl[wc * 32 + bq * 16 + l15][q8]);
        acc[aq][bq] = __builtin_amdgcn_mfma_f32_16x16x32_bf16(ah, bh, acc[aq][bq], 0, 0, 0);
        acc[aq][bq] = __builtin_amdgcn_mfma_f32_16x16x32_bf16(ah, bl, acc[aq][bq], 0, 0, 0);
        acc[aq][bq] = __builtin_amdgcn_mfma_f32_16x16x32_bf16(al, bh, acc[aq][bq], 0, 0, 0);
      }
    }
  }
#pragma unroll
  for (int aq = 0; aq < 2; ++aq)
#pragma unroll
    for (int bq = 0; bq < 2; ++bq)
#pragma unroll
      for (int r = 0; r < 4; ++r) {
        int gm = m0 + wr * 32 + aq * 16 + quad * 4 + r;
        int gn = n0 + wc * 32 + bq * 16 + l15;
        Cout[gm * 256 + gn] = alpha * acc[aq][bq][r] + ((addI && gm == gn) ? 1.0f : 0.0f);
      }
}

// ---------------------------------------------------------------------------
// Et_bf16[m][n] = AdT[m][n] - I ; A64[n][m] = A64T[m][n]
__global__ void k_convert(const float* __restrict__ AdT, const float* __restrict__ A64T,
                          unsigned short* __restrict__ Et, float* __restrict__ A64){
  int i = blockIdx.x * 256 + threadIdx.x;
  for (; i < 131072; i += gridDim.x * 256) {
    if (i < 65536) {
      int m = i >> 8, n = i & 255;
      Et[i] = f2bf(AdT[i] - (m == n ? 1.0f : 0.0f));
    } else {
      int o = i - 65536;
      A64[o] = A64T[(o & 255) * 256 + (o >> 8)];
    }
  }
}

// ---------------------------------------------------------------------------
// u_bf16 = bf16(x @ B) : M=16384, K=1024, N=256. grid(128,2)
__global__ __launch_bounds__(256) void k_gemm_u(const float* __restrict__ x,
                                                const unsigned short* __restrict__ Bt,
                                                unsigned short* __restrict__ u){
  __shared__ unsigned short Atile[128][40];
  __shared__ unsigned short Btile[128][40];
  int tid = threadIdx.x;
  int m0 = blockIdx.x * 128, n0 = blockIdx.y * 128;
  int w = tid >> 6, lane = tid & 63;
  int wr = w >> 1, wc = w & 1;
  int l15 = lane & 15, quad = lane >> 4;
  int q8 = quad * 8;
  f4v acc[4][4] = {};
  for (int kt = 0; kt < 1024; kt += 32) {
    __syncthreads();
#pragma unroll
    for (int q = 0; q < 4; ++q) {
      int id = q * 256 + tid;        // 1024 float4 total
      int row = id >> 3, c4 = id & 7;
      float4 vv = *reinterpret_cast<const float4*>(&x[(m0 + row) * 1024 + kt + c4 * 4]);
      ushort4 hv;
      hv.x = f2bf(vv.x); hv.y = f2bf(vv.y); hv.z = f2bf(vv.z); hv.w = f2bf(vv.w);
      *reinterpret_cast<ushort4*>(&Atile[row][c4 * 4]) = hv;
    }
#pragma unroll
    for (int q = 0; q < 2; ++q) {
      int id = q * 256 + tid;        // 512 uint4 total
      int row = id >> 2, c8 = id & 3;
      uint4 vv = *reinterpret_cast<const uint4*>(&Bt[(n0 + row) * 1024 + kt + c8 * 8]);
      *reinterpret_cast<uint4*>(&Btile[row][c8 * 8]) = vv;
    }
    __syncthreads();
    s8v af[4], bf[4];
#pragma unroll
    for (int aq = 0; aq < 4; ++aq)
      af[aq] = *reinterpret_cast<const s8v*>(&Atile[wr * 64 + aq * 16 + l15][q8]);
#pragma unroll
    for (int bq = 0; bq < 4; ++bq)
      bf[bq] = *reinterpret_cast<const s8v*>(&Btile[wc * 64 + bq * 16 + l15][q8]);
#pragma unroll
    for (int aq = 0; aq < 4; ++aq)
#pragma unroll
      for (int bq = 0; bq < 4; ++bq)
        acc[aq][bq] = __builtin_amdgcn_mfma_f32_16x16x32_bf16(af[aq], bf[bq], acc[aq][bq], 0, 0, 0);
  }
#pragma unroll
  for (int aq = 0; aq < 4; ++aq)
#pragma unroll
    for (int bq = 0; bq < 4; ++bq)
#pragma unroll
      for (int r = 0; r < 4; ++r) {
        int gm = m0 + wr * 64 + aq * 16 + quad * 4 + r;
        int gn = n0 + wc * 64 + bq * 16 + l15;
        u[gm * 256 + gn] = f2bf(acc[aq][bq][r]);
      }
}

// ---------------------------------------------------------------------------
// phase 1: per-(b,chunk) local scan h_t = h_{t-1} + h_{t-1}@E + u_t, zero init.
// 16 blocks x 16 units; writes hs (bf16 local states) and ff (f32 chunk finals).
__global__ __launch_bounds__(256, 1) void k_phase1(const unsigned short* __restrict__ u,
                                                   const unsigned short* __restrict__ Et,
                                                   unsigned short* __restrict__ hs,
                                                   float* __restrict__ ff){
  __shared__ unsigned short hbuf[2][16][264];
  int tid = threadIdx.x, w = tid >> 6, lane = tid & 63;
  int l15 = lane & 15, quad = lane >> 4;
  int U0 = blockIdx.x * 16;
  s8v e[4][8];
#pragma unroll
  for (int ct = 0; ct < 4; ++ct) {
    int col = w * 64 + ct * 16 + l15;
#pragma unroll
    for (int kt = 0; kt < 8; ++kt)
      e[ct][kt] = *reinterpret_cast<const s8v*>(&Et[col * 256 + kt * 32 + quad * 8]);
  }
  int rowbase[4];
#pragma unroll
  for (int r = 0; r < 4; ++r) {
    int g = U0 + quad * 4 + r;
    rowbase[r] = ((g >> 5) * 2048 + (g & 31) * 64) * 256;
  }
  for (int i = tid; i < 16 * 264; i += 256) hbuf[0][0][i] = 0;
  f4v acc[4] = {};
  __syncthreads();
  int cur = 0;
  for (int t = 0; t < LC; ++t) {
    s8v af[8];
#pragma unroll
    for (int kt = 0; kt < 8; ++kt)
      af[kt] = *reinterpret_cast<const s8v*>(&hbuf[cur][l15][kt * 32 + quad * 8]);
    float uv[4][4];
#pragma unroll
    for (int r = 0; r < 4; ++r)
#pragma unroll
      for (int ct = 0; ct < 4; ++ct)
        uv[r][ct] = bf2f(u[rowbase[r] + t * 256 + w * 64 + ct * 16 + l15]);
#pragma unroll
    for (int kt = 0; kt < 8; ++kt)
#pragma unroll
      for (int ct = 0; ct < 4; ++ct)
        acc[ct] = __builtin_amdgcn_mfma_f32_16x16x32_bf16(af[kt], e[ct][kt], acc[ct], 0, 0, 0);
    int nxt = cur ^ 1;
#pragma unroll
    for (int ct = 0; ct < 4; ++ct)
#pragma unroll
      for (int r = 0; r < 4; ++r) {
        acc[ct][r] += uv[r][ct];
        hbuf[nxt][quad * 4 + r][w * 64 + ct * 16 + l15] = f2bf(acc[ct][r]);
      }
    __syncthreads();
    int ul = w * 4 + quad, seg = l15;
    uint4 d0 = *reinterpret_cast<const uint4*>(&hbuf[nxt][ul][seg * 16]);
    uint4 d1 = *reinterpret_cast<const uint4*>(&hbuf[nxt][ul][seg * 16 + 8]);
    int g = U0 + ul;
    int hrow = ((g >> 5) * 2048 + (g & 31) * 64 + t) * 256;
    *reinterpret_cast<uint4*>(&hs[hrow + seg * 16]) = d0;
    *reinterpret_cast<uint4*>(&hs[hrow + seg * 16 + 8]) = d1;
    cur = nxt;
  }
#pragma unroll
  for (int ct = 0; ct < 4; ++ct)
#pragma unroll
    for (int r = 0; r < 4; ++r) {
      int g = U0 + quad * 4 + r;
      ff[(((g & 31) << 3) + (g >> 5)) * 256 + w * 64 + ct * 16 + l15] = acc[ct][r];
    }
}

// ---------------------------------------------------------------------------
// phase 2: f32 carry recurrence over chunks. 8 blocks (one per batch).
__global__ __launch_bounds__(256) void k_phase2(const float* __restrict__ h0,
                                                const float* __restrict__ ff,
                                                const float* __restrict__ A64,
                                                float* __restrict__ carry){
  __shared__ float cl[256];
  int b = blockIdx.x, m = threadIdx.x;
  float cm = h0[b * 256 + m];
  for (int c = 0; c < NC; ++c) {
    carry[(c * 8 + b) * 256 + m] = cm;
    __syncthreads();
    cl[m] = cm;
    __syncthreads();
    float a0 = ff[(c * 8 + b) * 256 + m];
    float a1 = 0.f, a2 = 0.f, a3 = 0.f;
#pragma unroll 8
    for (int n = 0; n < 256; n += 4) {
      a0 += cl[n]     * A64[n * 256 + m];
      a1 += cl[n + 1] * A64[(n + 1) * 256 + m];
      a2 += cl[n + 2] * A64[(n + 2) * 256 + m];
      a3 += cl[n + 3] * A64[(n + 3) * 256 + m];
    }
    cm = (a0 + a1) + (a2 + a3);
  }
}

// ---------------------------------------------------------------------------
// phase 3: carry expansion scan: acc_t = acc_{t-1} + acc_{t-1}@E (acc_0=carry),
// RMW hs[t] += acc_t.  Same structure as phase 1.
__global__ __launch_bounds__(256, 1) void k_phase3(const float* __restrict__ carry,
                                                   const unsigned short* __restrict__ Et,
                                                   unsigned short* __restrict__ hs){
  __shared__ unsigned short hbuf[2][16][264];
  int tid = threadIdx.x, w = tid >> 6, lane = tid & 63;
  int l15 = lane & 15, quad = lane >> 4;
  int U0 = blockIdx.x * 16;
  s8v e[4][8];
#pragma unroll
  for (int ct = 0; ct < 4; ++ct) {
    int col = w * 64 + ct * 16 + l15;
#pragma unroll
    for (int kt = 0; kt < 8; ++kt)
      e[ct][kt] = *reinterpret_cast<const s8v*>(&Et[col * 256 + kt * 32 + quad * 8]);
  }
  f4v acc[4];
#pragma unroll
  for (int ct = 0; ct < 4; ++ct)
#pragma unroll
    for (int r = 0; r < 4; ++r) {
      int g = U0 + quad * 4 + r;
      acc[ct][r] = carry[(((g & 31) << 3) + (g >> 5)) * 256 + w * 64 + ct * 16 + l15];
      hbuf[0][quad * 4 + r][w * 64 + ct * 16 + l15] = f2bf(acc[ct][r]);
    }
  __syncthreads();
  int cur = 0;
  for (int t = 0; t < LC; ++t) {
    s8v af[8];
#pragma unroll
    for (int kt = 0; kt < 8; ++kt)
      af[kt] = *reinterpret_cast<const s8v*>(&hbuf[cur][l15][kt * 32 + quad * 8]);
#pragma unroll
    for (int kt = 0; kt < 8; ++kt)
#pragma unroll
      for (int ct = 0; ct < 4; ++ct)
        acc[ct] = __builtin_amdgcn_mfma_f32_16x16x32_bf16(af[kt], e[ct][kt], acc[ct], 0, 0, 0);
    int nxt = cur ^ 1;
#pragma unroll
    for (int ct = 0; ct < 4; ++ct)
#pragma unroll
      for (int r = 0; r < 4; ++r)
        hbuf[nxt][quad * 4 + r][w * 64 + ct * 16 + l15] = f2bf(acc[ct][r]);
    __syncthreads();
    int ul = w * 4 + quad, seg = l15;
    uint4 d0 = *reinterpret_cast<const uint4*>(&hbuf[nxt][ul][seg * 16]);
    uint4 d1 = *reinterpret_cast<const uint4*>(&hbuf[nxt][ul][seg * 16 + 8]);
    int g = U0 + ul;
    int hrow = ((g >> 5) * 2048 + (g & 31) * 64 + t) * 256;
    uint4 o0 = *reinterpret_cast<const uint4*>(&hs[hrow + seg * 16]);
    uint4 o1 = *reinterpret_cast<const uint4*>(&hs[hrow + seg * 16 + 8]);
    uint4 s0, s1;
    s0.x = addbf2(d0.x, o0.x); s0.y = addbf2(d0.y, o0.y);
    s0.z = addbf2(d0.z, o0.z); s0.w = addbf2(d0.w, o0.w);
    s1.x = addbf2(d1.x, o1.x); s1.y = addbf2(d1.y, o1.y);
    s1.z = addbf2(d1.z, o1.z); s1.w = addbf2(d1.w, o1.w);
    *reinterpret_cast<uint4*>(&hs[hrow + seg * 16]) = s0;
    *reinterpret_cast<uint4*>(&hs[hrow + seg * 16 + 8]) = s1;
    cur = nxt;
  }
}

// ---------------------------------------------------------------------------
// y = hs @ C + x*D : M=16384, K=256, N=1024. grid(128,8)
__global__ __launch_bounds__(256) void k_gemm_y(const unsigned short* __restrict__ hs,
                                                const unsigned short* __restrict__ Ct,
                                                const float* __restrict__ x,
                                                const float* __restrict__ D,
                                                float* __restrict__ y){
  __shared__ unsigned short Atile[128][40];
  __shared__ unsigned short Btile[128][40];
  int tid = threadIdx.x;
  int m0 = blockIdx.x * 128, n0 = blockIdx.y * 128;
  int w = tid >> 6, lane = tid & 63;
  int wr = w >> 1, wc = w & 1;
  int l15 = lane & 15, quad = lane >> 4;
  int q8 = quad * 8;
  f4v acc[4][4] = {};
  for (int kt = 0; kt < 256; kt += 32) {
    __syncthreads();
#pragma unroll
    for (int q = 0; q < 2; ++q) {
      int id = q * 256 + tid;
      int row = id >> 2, c8 = id & 3;
      uint4 av = *reinterpret_cast<const uint4*>(&hs[(m0 + row) * 256 + kt + c8 * 8]);
      *reinterpret_cast<uint4*>(&Atile[row][c8 * 8]) = av;
      uint4 bv = *reinterpret_cast<const uint4*>(&Ct[(n0 + row) * 256 + kt + c8 * 8]);
      *reinterpret_cast<uint4*>(&Btile[row][c8 * 8]) = bv;
    }
    __syncthreads();
    s8v af[4], bf[4];
#pragma unroll
    for (int aq = 0; aq < 4; ++aq)
      af[aq] = *reinterpret_cast<const s8v*>(&Atile[wr * 64 + aq * 16 + l15][q8]);
#pragma unroll
    for (int bq = 0; bq < 4; ++bq)
      bf[bq] = *reinterpret_cast<const s8v*>(&Btile[wc * 64 + bq * 16 + l15][q8]);
#pragma unroll
    for (int aq = 0; aq < 4; ++aq)
#pragma unroll
      for (int bq = 0; bq < 4; ++bq)
        acc[aq][bq] = __builtin_amdgcn_mfma_f32_16x16x32_bf16(af[aq], bf[bq], acc[aq][bq], 0, 0, 0);
  }
#pragma unroll
  for (int bq = 0; bq < 4; ++bq) {
    int gn = n0 + wc * 64 + bq * 16 + l15;
    float dv = D[gn];
#pragma unroll
    for (int aq = 0; aq < 4; ++aq)
#pragma unroll
      for (int r = 0; r < 4; ++r) {
        int gm = m0 + wr * 64 + aq * 16 + quad * 4 + r;
        y[gm * 1024 + gn] = acc[aq][bq][r] + x[gm * 1024 + gn] * dv;
      }
  }
}

// ---------------------------------------------------------------------------
extern "C" void kernel_launch(void* const* d_in, const int* in_sizes, int n_in,
                              void* d_out, int out_size, void* d_ws, size_t ws_size,
                              hipStream_t stream) {
  (void)in_sizes; (void)n_in; (void)out_size; (void)ws_size;
  const float* x  = (const float*)d_in[0];
  const float* A  = (const float*)d_in[1];
  const float* B  = (const float*)d_in[2];
  const float* C  = (const float*)d_in[3];
  const float* D  = (const float*)d_in[4];
  const float* h0 = (const float*)d_in[5];
  float* y = (float*)d_out;

  char* ws = (char*)d_ws;
  size_t off = 0;
  auto alloc = [&](size_t bytes) { void* p = ws + off; off += (bytes + 255) & ~(size_t)255; return p; };
  float* Ttmp0 = (float*)alloc(262144);
  float* Ttmp1 = (float*)alloc(262144);
  float* Mt    = (float*)alloc(262144);
  float* AdT   = (float*)alloc(262144);
  float* A64T  = (float*)alloc(262144);
  float* A64   = (float*)alloc(262144);
  unsigned short* Et = (unsigned short*)alloc(131072);
  float* carry = (float*)alloc(262144);
  float* ff    = (float*)alloc(262144);
  unsigned short* Bt = (unsigned short*)alloc(524288);
  unsigned short* Ct = (unsigned short*)alloc(524288);
  unsigned short* u  = (unsigned short*)alloc(8388608);
  unsigned short* hs = (unsigned short*)alloc(8388608);

  k_prep<<<2304, 256, 0, stream>>>(A, B, C, Mt, Ttmp0, Bt, Ct);

  dim3 g44(4, 4);
  // Taylor (Horner, 6 terms): T0 already = I + Mt/6
  k_gemm256_hl<<<g44, 256, 0, stream>>>(Mt, Ttmp0, Ttmp1, 1.0f / 5.0f, 1);
  k_gemm256_hl<<<g44, 256, 0, stream>>>(Mt, Ttmp1, Ttmp0, 1.0f / 4.0f, 1);
  k_gemm256_hl<<<g44, 256, 0, stream>>>(Mt, Ttmp0, Ttmp1, 1.0f / 3.0f, 1);
  k_gemm256_hl<<<g44, 256, 0, stream>>>(Mt, Ttmp1, Ttmp0, 1.0f / 2.0f, 1);
  k_gemm256_hl<<<g44, 256, 0, stream>>>(Mt, Ttmp0, AdT, 1.0f, 1);
  // squarings: AdT -> A64T  (A_d^T squared 6 times)
  k_gemm256_hl<<<g44, 256, 0, stream>>>(AdT, AdT, Ttmp0, 1.0f, 0);
  k_gemm256_hl<<<g44, 256, 0, stream>>>(Ttmp0, Ttmp0, Ttmp1, 1.0f, 0);
  k_gemm256_hl<<<g44, 256, 0, stream>>>(Ttmp1, Ttmp1, Ttmp0, 1.0f, 0);
  k_gemm256_hl<<<g44, 256, 0, stream>>>(Ttmp0, Ttmp0, Ttmp1, 1.0f, 0);
  k_gemm256_hl<<<g44, 256, 0, stream>>>(Ttmp1, Ttmp1, Ttmp0, 1.0f, 0);
  k_gemm256_hl<<<g44, 256, 0, stream>>>(Ttmp0, Ttmp0, A64T, 1.0f, 0);

  k_convert<<<512, 256, 0, stream>>>(AdT, A64T, Et, A64);

  k_gemm_u<<<dim3(128, 2), 256, 0, stream>>>(x, Bt, u);
  k_phase1<<<16, 256, 0, stream>>>(u, Et, hs, ff);
  k_phase2<<<8, 256, 0, stream>>>(h0, ff, A64, carry);
  k_phase3<<<16, 256, 0, stream>>>(carry, Et, hs);
  k_gemm_y<<<dim3(128, 8), 256, 0, stream>>>(hs, Ct, x, D, y);
}